// Round 1
// baseline (3517.665 us; speedup 1.0000x reference)
//
#include <hip/hip_runtime.h>
#include <cstdint>
#include <cstddef>

// Problem constants
#define B_   4
#define S_   1024
#define D_   1024
#define H_   16
#define DH_  64
#define DFF_ 4096
#define M_   (B_ * S_)   // 4096 rows for all linears

// ---------------------------------------------------------------------------
// GEMM: Y[M,N] = A[M,K] @ Wt[N,K]^T + bias[N]   (optional exact GELU)
// 128x128 tile, BK=16, 256 threads, 8x8 per thread, fp32.
// ---------------------------------------------------------------------------
template <int GELU>
__global__ __launch_bounds__(256)
void gemm_bias_k(const float* __restrict__ A, const float* __restrict__ Wt,
                 const float* __restrict__ bias, float* __restrict__ Y,
                 int M, int N, int K) {
  constexpr int BM = 128, BN = 128, BK = 16;
  __shared__ float sA[BK][BM + 4];   // k-major: sA[k][m]
  __shared__ float sB[BK][BN + 4];   // k-major: sB[k][n]

  const int t  = threadIdx.x;
  const int tx = t & 15;        // 0..15 -> n sub-tile
  const int ty = t >> 4;        // 0..15 -> m sub-tile
  const int m0 = blockIdx.y * BM;
  const int n0 = blockIdx.x * BN;

  // loader mapping: each thread loads 2 rows (lm, lm+64), 4 contiguous k
  const int lm = t >> 2;          // 0..63
  const int lk = (t & 3) << 2;    // 0,4,8,12

  float acc[8][8];
#pragma unroll
  for (int i = 0; i < 8; ++i)
#pragma unroll
    for (int j = 0; j < 8; ++j) acc[i][j] = 0.f;

  for (int k0 = 0; k0 < K; k0 += BK) {
    __syncthreads();   // previous iteration's reads done before overwrite
#pragma unroll
    for (int p = 0; p < 2; ++p) {
      const float4 va = *(const float4*)(A + (size_t)(m0 + lm + p * 64) * K + k0 + lk);
      sA[lk + 0][lm + p * 64] = va.x;
      sA[lk + 1][lm + p * 64] = va.y;
      sA[lk + 2][lm + p * 64] = va.z;
      sA[lk + 3][lm + p * 64] = va.w;
      const float4 vb = *(const float4*)(Wt + (size_t)(n0 + lm + p * 64) * K + k0 + lk);
      sB[lk + 0][lm + p * 64] = vb.x;
      sB[lk + 1][lm + p * 64] = vb.y;
      sB[lk + 2][lm + p * 64] = vb.z;
      sB[lk + 3][lm + p * 64] = vb.w;
    }
    __syncthreads();

#pragma unroll
    for (int k = 0; k < BK; ++k) {
      const float4 a0 = *(const float4*)&sA[k][ty * 8];
      const float4 a1 = *(const float4*)&sA[k][ty * 8 + 4];
      const float4 b0 = *(const float4*)&sB[k][tx * 8];
      const float4 b1 = *(const float4*)&sB[k][tx * 8 + 4];
      const float av[8] = {a0.x, a0.y, a0.z, a0.w, a1.x, a1.y, a1.z, a1.w};
      const float bv[8] = {b0.x, b0.y, b0.z, b0.w, b1.x, b1.y, b1.z, b1.w};
#pragma unroll
      for (int i = 0; i < 8; ++i)
#pragma unroll
        for (int j = 0; j < 8; ++j) acc[i][j] += av[i] * bv[j];
    }
  }

  // epilogue: bias (+ GELU), vectorized store
#pragma unroll
  for (int i = 0; i < 8; ++i) {
    const size_t m = (size_t)(m0 + ty * 8 + i);
    float v[8];
#pragma unroll
    for (int j = 0; j < 8; ++j) {
      float x = acc[i][j] + bias[n0 + tx * 8 + j];
      if (GELU) x = 0.5f * x * (1.0f + erff(x * 0.70710678118654752f));
      v[j] = x;
    }
    float4 r0 = {v[0], v[1], v[2], v[3]};
    float4 r1 = {v[4], v[5], v[6], v[7]};
    *(float4*)(Y + m * N + n0 + tx * 8)     = r0;
    *(float4*)(Y + m * N + n0 + tx * 8 + 4) = r1;
  }
}

// ---------------------------------------------------------------------------
// Flash-style attention (fp32), full (unmasked) softmax:
//   O[b,q,h*64+d] = (softmax(Q K^T / 8) @ V)[q,d]  (+ optional addend)
// Q,K,V,O all [B*S, D] with head h in columns [h*64, h*64+64).
// Block: 256 threads = 32 q-rows x 8 threads. grid = B*H*(S/32).
// ---------------------------------------------------------------------------
__global__ __launch_bounds__(256)
void attn_k(const float* __restrict__ Q, const float* __restrict__ Kt,
            const float* __restrict__ Vt, const float* __restrict__ addend,
            float* __restrict__ O) {
  constexpr int QT = 32, KT = 64;
  __shared__ float sQ[QT][68];   // padded: conflict-free row reads
  __shared__ float sK[KT][64];   // XOR-swizzled 16B chunks
  __shared__ float sV[KT][64];   // linear (reads are 2-way max = free)
  __shared__ float sP[QT][68];   // padded probs tile

  const int t   = threadIdx.x;
  const int sub = t & 7;     // 0..7: owns dims sub*8..sub*8+7 and scores j=sub*8..+7
  const int r   = t >> 3;    // 0..31: q-row within tile

  const int nqt = S_ / QT;                   // 32
  const int qt  = blockIdx.x % nqt;
  const int h   = (blockIdx.x / nqt) % H_;
  const int b   = blockIdx.x / (nqt * H_);
  const size_t rowbase = (size_t)b * S_;
  const int    col0    = h * DH_;

  // load Q tile
  {
    const float* src = Q + (rowbase + qt * QT + r) * D_ + col0 + sub * 8;
    *(float4*)&sQ[r][sub * 8]     = *(const float4*)(src);
    *(float4*)&sQ[r][sub * 8 + 4] = *(const float4*)(src + 4);
  }

  float m = -1e30f, l = 0.f;
  float o[8];
#pragma unroll
  for (int i = 0; i < 8; ++i) o[i] = 0.f;

  // loader mapping for K/V tiles: 64 rows, 4 threads/row, 16 floats each
  const int lr  = t >> 2;          // 0..63
  const int lc4 = (t & 3) << 2;    // chunk base (chunks of 4 floats): 0,4,8,12

  for (int kt = 0; kt < S_; kt += KT) {
    __syncthreads();   // previous PV done before overwriting K/V
    {
      const float* ksrc = Kt + (rowbase + kt + lr) * D_ + col0 + (lc4 << 2);
      const float* vsrc = Vt + (rowbase + kt + lr) * D_ + col0 + (lc4 << 2);
#pragma unroll
      for (int i = 0; i < 4; ++i) {
        const float4 kv = *(const float4*)(ksrc + i * 4);
        const int c  = lc4 + i;
        const int cs = c ^ (lr >> 3);                 // swizzle 16B chunks
        *(float4*)&sK[lr][cs << 2] = kv;
        const float4 vv = *(const float4*)(vsrc + i * 4);
        *(float4*)&sV[lr][c << 2] = vv;
      }
    }
    __syncthreads();

    // scores for j = sub*8 .. sub*8+7
    float s[8];
#pragma unroll
    for (int jj = 0; jj < 8; ++jj) s[jj] = 0.f;
#pragma unroll
    for (int kc = 0; kc < 16; ++kc) {
      const float4 qv = *(const float4*)&sQ[r][kc << 2];
      const int cs = kc ^ sub;    // rows sub*8+jj have (row>>3)==sub
#pragma unroll
      for (int jj = 0; jj < 8; ++jj) {
        const float4 kv = *(const float4*)&sK[(sub << 3) + jj][cs << 2];
        s[jj] += qv.x * kv.x + qv.y * kv.y + qv.z * kv.z + qv.w * kv.w;
      }
    }

    // online softmax within the 8-lane group
    float tmax = -1e30f;
#pragma unroll
    for (int jj = 0; jj < 8; ++jj) {
      s[jj] *= 0.125f;   // 1/sqrt(64)
      tmax = fmaxf(tmax, s[jj]);
    }
    tmax = fmaxf(tmax, __shfl_xor(tmax, 1));
    tmax = fmaxf(tmax, __shfl_xor(tmax, 2));
    tmax = fmaxf(tmax, __shfl_xor(tmax, 4));

    const float mn = fmaxf(m, tmax);
    const float cr = expf(m - mn);
    float p[8];
    float tsum = 0.f;
#pragma unroll
    for (int jj = 0; jj < 8; ++jj) {
      p[jj] = expf(s[jj] - mn);
      tsum += p[jj];
    }
    tsum += __shfl_xor(tsum, 1);
    tsum += __shfl_xor(tsum, 2);
    tsum += __shfl_xor(tsum, 4);
    l = l * cr + tsum;
    m = mn;
#pragma unroll
    for (int i = 0; i < 8; ++i) o[i] *= cr;
#pragma unroll
    for (int jj = 0; jj < 8; ++jj) sP[r][(sub << 3) + jj] = p[jj];
    __syncthreads();

    // PV: o[d] += sum_j P[r][j] * V[j][d]
    for (int j = 0; j < KT; ++j) {
      const float pj = sP[r][j];
      const float4 v0 = *(const float4*)&sV[j][sub << 3];
      const float4 v1 = *(const float4*)&sV[j][(sub << 3) + 4];
      o[0] += pj * v0.x; o[1] += pj * v0.y; o[2] += pj * v0.z; o[3] += pj * v0.w;
      o[4] += pj * v1.x; o[5] += pj * v1.y; o[6] += pj * v1.z; o[7] += pj * v1.w;
    }
  }

  const float inv = 1.0f / l;
  const size_t off = (rowbase + qt * QT + r) * D_ + col0 + (sub << 3);
  float res[8];
#pragma unroll
  for (int i = 0; i < 8; ++i) res[i] = o[i] * inv;
  if (addend != nullptr) {
    const float4 a0 = *(const float4*)(addend + off);
    const float4 a1 = *(const float4*)(addend + off + 4);
    res[0] += a0.x; res[1] += a0.y; res[2] += a0.z; res[3] += a0.w;
    res[4] += a1.x; res[5] += a1.y; res[6] += a1.z; res[7] += a1.w;
  }
  float4 r0 = {res[0], res[1], res[2], res[3]};
  float4 r1 = {res[4], res[5], res[6], res[7]};
  *(float4*)(O + off)     = r0;
  *(float4*)(O + off + 4) = r1;
}

// ---------------------------------------------------------------------------
// Host-side orchestration
// ---------------------------------------------------------------------------
extern "C" void kernel_launch(void* const* d_in, const int* in_sizes, int n_in,
                              void* d_out, int out_size, void* d_ws, size_t ws_size,
                              hipStream_t stream) {
  const float* gf = (const float*)d_in[0];   // global_feat
  const float* lf = (const float*)d_in[1];   // local_feat
  const float* tf = (const float*)d_in[2];   // text_feat
  const float* ge_w  = (const float*)d_in[3],  *ge_b  = (const float*)d_in[4];
  const float* le1_w = (const float*)d_in[5],  *le1_b = (const float*)d_in[6];
  const float* le2_w = (const float*)d_in[7],  *le2_b = (const float*)d_in[8];
  const float* qg_w  = (const float*)d_in[9],  *qg_b  = (const float*)d_in[10];
  const float* kg_w  = (const float*)d_in[11], *kg_b  = (const float*)d_in[12];
  const float* vg_w  = (const float*)d_in[13], *vg_b  = (const float*)d_in[14];
  const float* qp_w  = (const float*)d_in[15], *qp_b  = (const float*)d_in[16];
  const float* kp_w  = (const float*)d_in[17], *kp_b  = (const float*)d_in[18];
  const float* vp_w  = (const float*)d_in[19], *vp_b  = (const float*)d_in[20];
  const float* dense_w = (const float*)d_in[21], *dense_b = (const float*)d_in[22];
  const float* ml_w  = (const float*)d_in[23], *ml_b  = (const float*)d_in[24];
  const float* fc1_w = (const float*)d_in[25], *fc1_b = (const float*)d_in[26];
  const float* fc2_w = (const float*)d_in[27], *fc2_b = (const float*)d_in[28];

  float* out = (float*)d_out;

  // workspace layout: 9 x [B*S,D] slots + 1 x [B*S,DFF] = 208 MiB total
  const size_t SLOT = (size_t)M_ * D_;   // 4 Mi floats = 16 MiB
  float* W = (float*)d_ws;
  float* glob = W + 0 * SLOT;   // later reused for `last`
  float* loc  = W + 1 * SLOT;   // later reused for `out1`
  float* dup  = W + 2 * SLOT;   // later reused for `u`
  float* qgb  = W + 3 * SLOT;   // later reused for `out2`
  float* kgb  = W + 4 * SLOT;
  float* vgb  = W + 5 * SLOT;
  float* qpb  = W + 6 * SLOT;
  float* kpb  = W + 7 * SLOT;
  float* vpb  = W + 8 * SLOT;
  float* hbuf = W + 9 * SLOT;   // [4096, 4096] = 64 MiB

  const dim3 blk(256);
  const dim3 gDD(D_ / 128, M_ / 128);     // N=1024 outputs: 8 x 32
  const dim3 gDF(DFF_ / 128, M_ / 128);   // N=4096 outputs: 32 x 32

  // embeddings
  hipLaunchKernelGGL((gemm_bias_k<0>), gDD, blk, 0, stream, gf, ge_w,  ge_b,  glob, M_, D_, D_);
  hipLaunchKernelGGL((gemm_bias_k<0>), gDD, blk, 0, stream, lf, le1_w, le1_b, dup,  M_, D_, D_);
  hipLaunchKernelGGL((gemm_bias_k<0>), gDD, blk, 0, stream, lf, le2_w, le2_b, loc,  M_, D_, D_);

  // projections
  hipLaunchKernelGGL((gemm_bias_k<0>), gDD, blk, 0, stream, glob, qg_w, qg_b, qgb, M_, D_, D_);
  hipLaunchKernelGGL((gemm_bias_k<0>), gDD, blk, 0, stream, loc,  kg_w, kg_b, kgb, M_, D_, D_);
  hipLaunchKernelGGL((gemm_bias_k<0>), gDD, blk, 0, stream, loc,  vg_w, vg_b, vgb, M_, D_, D_);
  hipLaunchKernelGGL((gemm_bias_k<0>), gDD, blk, 0, stream, dup,  qp_w, qp_b, qpb, M_, D_, D_);
  hipLaunchKernelGGL((gemm_bias_k<0>), gDD, blk, 0, stream, tf,   kp_w, kp_b, kpb, M_, D_, D_);
  hipLaunchKernelGGL((gemm_bias_k<0>), gDD, blk, 0, stream, tf,   vp_w, vp_b, vpb, M_, D_, D_);

  // attention with bridge collapsed by associativity:
  //   u    = vg + softmax(qp kp^T /8) @ vp
  //   last = softmax(qg kg^T /8) @ u
  const int attnGrid = B_ * H_ * (S_ / 32);   // 2048
  float* u    = dup;    // reuse
  float* last = glob;   // reuse
  hipLaunchKernelGGL(attn_k, dim3(attnGrid), blk, 0, stream, qpb, kpb, vpb, vgb, u);
  hipLaunchKernelGGL(attn_k, dim3(attnGrid), blk, 0, stream, qgb, kgb, u, (const float*)nullptr, last);

  // output projections + MLP
  float* out1 = loc;    // reuse
  float* out2 = qgb;    // reuse
  hipLaunchKernelGGL((gemm_bias_k<0>), gDD, blk, 0, stream, last, dense_w, dense_b, out1, M_, D_, D_);
  hipLaunchKernelGGL((gemm_bias_k<1>), gDF, blk, 0, stream, out1, fc1_w, fc1_b, hbuf, M_, DFF_, D_);
  hipLaunchKernelGGL((gemm_bias_k<0>), gDD, blk, 0, stream, hbuf, fc2_w, fc2_b, out2, M_, D_, DFF_);
  hipLaunchKernelGGL((gemm_bias_k<0>), gDD, blk, 0, stream, out2, ml_w, ml_b, out, M_, D_, D_);
}

// Round 5
// 1548.789 us; speedup vs baseline: 2.2712x; 2.2712x over previous
//
#include <hip/hip_runtime.h>
#include <cstdint>
#include <cstddef>

// Problem constants
#define B_   4
#define S_   1024
#define D_   1024
#define H_   16
#define DH_  64
#define DFF_ 4096
#define M_   (B_ * S_)   // 4096 rows for all linears

typedef __bf16 bf16x8 __attribute__((ext_vector_type(8)));
typedef float  f32x4  __attribute__((ext_vector_type(4)));

__device__ __forceinline__ unsigned short f2bf(float f) {
  unsigned int u = __float_as_uint(f);
  u = (u + 0x7fffu + ((u >> 16) & 1u)) >> 16;   // round-to-nearest-even
  return (unsigned short)u;
}

__device__ __forceinline__ float bf2f(unsigned short h) {
  return __uint_as_float(((unsigned int)h) << 16);
}

// async global->LDS, 16B per lane; LDS dest must be wave-uniform base (+lane*16)
__device__ __forceinline__ void gload_lds16(const void* g, void* l) {
  __builtin_amdgcn_global_load_lds((const __attribute__((address_space(1))) void*)g,
                                   (__attribute__((address_space(3))) void*)l, 16, 0, 0);
}

// ---------------------------------------------------------------------------
// Fused f32 -> bf16 conversion for up to 16 tensors in one launch
// ---------------------------------------------------------------------------
#define NCVT 16
struct CvtB { const float* s[NCVT]; unsigned short* d[NCVT]; int n[NCVT]; };

__global__ __launch_bounds__(256)
void cvt_k(CvtB cb) {
  const int z = blockIdx.y;
  const float* __restrict__ s = cb.s[z];
  unsigned short* __restrict__ d = cb.d[z];
  const int n = cb.n[z];
  const int stride = gridDim.x * 256 * 4;
  for (int i = (blockIdx.x * 256 + threadIdx.x) * 4; i < n; i += stride) {
    const float4 v = *(const float4*)(s + i);
    const unsigned int a = (unsigned int)f2bf(v.x) | ((unsigned int)f2bf(v.y) << 16);
    const unsigned int b = (unsigned int)f2bf(v.z) | ((unsigned int)f2bf(v.w) << 16);
    *(uint2*)(d + i) = make_uint2(a, b);
  }
}

// ---------------------------------------------------------------------------
// Batched MFMA GEMM: Y[M,N] = A[M,K] @ W[N,K]^T + bias  (bf16 in, f32 acc)
// m97 structure: 128x128 tile, BK=32, 256 thr (4 waves, 2x2), 4x4 16x16x32
// frags per wave, global_load_lds width=16 staging, single LDS buffer.
// blockIdx.z selects the batch member (independent same-shape GEMMs).
// ---------------------------------------------------------------------------
#define MAXB 6
struct GemmB {
  const unsigned short* A[MAXB];
  const unsigned short* W[MAXB];
  const float*          bias[MAXB];
  void*                 Y[MAXB];
};

template <int GELU, int OUTF32>
__global__ __launch_bounds__(256)
void mgemm(GemmB gb, int M, int N, int K) {
  __shared__ unsigned short sA[128][32];   // [row][k] bf16, 64 B rows (8 KB)
  __shared__ unsigned short sB[128][32];   // [col][k] bf16 (W is [N,K])

  const int z = blockIdx.z;
  const unsigned short* __restrict__ A = gb.A[z];
  const unsigned short* __restrict__ W = gb.W[z];
  const float* __restrict__ bias = gb.bias[z];

  const int t  = threadIdx.x;
  const int ln = t & 63;
  const int wv = t >> 6;          // wave 0..3
  const int wr = wv >> 1;         // wave row (0..1) -> 64 output rows
  const int wc = wv & 1;          // wave col (0..1) -> 64 output cols
  const int m0 = blockIdx.y * 128;
  const int n0 = blockIdx.x * 128;

  // staging mapping: chunk c = 16 rows (1024 B); lane covers bytes lane*16
  const int srow  = ln >> 2;        // row within chunk
  const int skoff = (ln & 3) << 3;  // k offset (elements)

  f32x4 acc[4][4] = {};

  char* sAb = (char*)&sA[0][0];
  char* sBb = (char*)&sB[0][0];

  for (int k0 = 0; k0 < K; k0 += 32) {
    __syncthreads();    // previous compute's LDS reads done
#pragma unroll
    for (int i = 0; i < 2; ++i) {
      const int c = (wv << 1) | i;    // this wave's chunks
      gload_lds16(A + (size_t)(m0 + (c << 4) + srow) * K + k0 + skoff, sAb + (c << 10));
      gload_lds16(W + (size_t)(n0 + (c << 4) + srow) * K + k0 + skoff, sBb + (c << 10));
    }
    __syncthreads();    // compiler drains vmcnt before barrier -> tiles ready

    // fragment reads: lane l -> row (l&15), k (l>>4)*8 .. +7  (16 B)
    const int rsel = ln & 15;
    const int csel = (ln >> 4) << 4;   // byte offset in 64 B row
    bf16x8 av[4], bv[4];
#pragma unroll
    for (int m = 0; m < 4; ++m)
      av[m] = *(const bf16x8*)(sAb + (((wr << 6) + (m << 4) + rsel) << 6) + csel);
#pragma unroll
    for (int n = 0; n < 4; ++n)
      bv[n] = *(const bf16x8*)(sBb + (((wc << 6) + (n << 4) + rsel) << 6) + csel);

#pragma unroll
    for (int m = 0; m < 4; ++m)
#pragma unroll
      for (int n = 0; n < 4; ++n)
        acc[m][n] = __builtin_amdgcn_mfma_f32_16x16x32_bf16(av[m], bv[n], acc[m][n], 0, 0, 0);
  }

  // epilogue: C/D layout col = lane&15, row = (lane>>4)*4 + reg
  const int rbase = m0 + (wr << 6) + ((ln >> 4) << 2);
  const int cb0   = n0 + (wc << 6) + (ln & 15);
#pragma unroll
  for (int m = 0; m < 4; ++m) {
#pragma unroll
    for (int n = 0; n < 4; ++n) {
      const int col = cb0 + (n << 4);
      const float bi = bias[col];
#pragma unroll
      for (int j = 0; j < 4; ++j) {
        const int row = rbase + (m << 4) + j;
        float x = acc[m][n][j] + bi;
        if (GELU) x = 0.5f * x * (1.0f + erff(x * 0.70710678118654752f));
        if (OUTF32) ((float*)gb.Y[z])[(size_t)row * N + col] = x;
        else        ((unsigned short*)gb.Y[z])[(size_t)row * N + col] = f2bf(x);
      }
    }
  }
}

// ---------------------------------------------------------------------------
// Flash-style attention, fp32 compute, bf16 I/O:
//   O = softmax(Q K^T / 8) @ V  (+ optional addend), per (b, head)
// Unchanged structure from the passing fp32 version; only load/store dtype.
// ---------------------------------------------------------------------------
__device__ __forceinline__ void unpack8(uint4 v, float* o) {
  const unsigned int u[4] = {v.x, v.y, v.z, v.w};
#pragma unroll
  for (int i = 0; i < 4; ++i) {
    o[2 * i]     = __uint_as_float(u[i] << 16);
    o[2 * i + 1] = __uint_as_float(u[i] & 0xffff0000u);
  }
}

__global__ __launch_bounds__(256)
void attn_k(const unsigned short* __restrict__ Q, const unsigned short* __restrict__ Kt,
            const unsigned short* __restrict__ Vt, const unsigned short* __restrict__ addend,
            unsigned short* __restrict__ O) {
  constexpr int QT = 32, KT = 64;
  __shared__ float sQ[QT][68];
  __shared__ float sK[KT][64];   // XOR-swizzled 16 B chunks
  __shared__ float sV[KT][64];
  __shared__ float sP[QT][68];

  const int t   = threadIdx.x;
  const int sub = t & 7;
  const int r   = t >> 3;

  const int nqt = S_ / QT;
  const int qt  = blockIdx.x % nqt;
  const int h   = (blockIdx.x / nqt) % H_;
  const int b   = blockIdx.x / (nqt * H_);
  const size_t rowbase = (size_t)b * S_;
  const int    col0    = h * DH_;

  {
    const unsigned short* src = Q + (rowbase + qt * QT + r) * D_ + col0 + sub * 8;
    unpack8(*(const uint4*)src, &sQ[r][sub * 8]);
  }

  float m = -1e30f, l = 0.f;
  float o[8];
#pragma unroll
  for (int i = 0; i < 8; ++i) o[i] = 0.f;

  const int lr  = t >> 2;
  const int lc4 = (t & 3) << 2;

  for (int kt = 0; kt < S_; kt += KT) {
    __syncthreads();
    {
      const unsigned short* ksrc = Kt + (rowbase + kt + lr) * D_ + col0 + (lc4 << 2);
      const unsigned short* vsrc = Vt + (rowbase + kt + lr) * D_ + col0 + (lc4 << 2);
      float kf[16], vf[16];
      unpack8(*(const uint4*)ksrc,       kf);
      unpack8(*(const uint4*)(ksrc + 8), kf + 8);
      unpack8(*(const uint4*)vsrc,       vf);
      unpack8(*(const uint4*)(vsrc + 8), vf + 8);
#pragma unroll
      for (int i = 0; i < 4; ++i) {
        const int c  = lc4 + i;
        const int cs = c ^ (lr >> 3);
        float4 kq = {kf[4 * i], kf[4 * i + 1], kf[4 * i + 2], kf[4 * i + 3]};
        float4 vq = {vf[4 * i], vf[4 * i + 1], vf[4 * i + 2], vf[4 * i + 3]};
        *(float4*)&sK[lr][cs << 2] = kq;
        *(float4*)&sV[lr][c << 2]  = vq;
      }
    }
    __syncthreads();

    float s[8];
#pragma unroll
    for (int jj = 0; jj < 8; ++jj) s[jj] = 0.f;
#pragma unroll
    for (int kc = 0; kc < 16; ++kc) {
      const float4 qv = *(const float4*)&sQ[r][kc << 2];
      const int cs = kc ^ sub;
#pragma unroll
      for (int jj = 0; jj < 8; ++jj) {
        const float4 kv = *(const float4*)&sK[(sub << 3) + jj][cs << 2];
        s[jj] += qv.x * kv.x + qv.y * kv.y + qv.z * kv.z + qv.w * kv.w;
      }
    }

    float tmax = -1e30f;
#pragma unroll
    for (int jj = 0; jj < 8; ++jj) {
      s[jj] *= 0.125f;
      tmax = fmaxf(tmax, s[jj]);
    }
    tmax = fmaxf(tmax, __shfl_xor(tmax, 1));
    tmax = fmaxf(tmax, __shfl_xor(tmax, 2));
    tmax = fmaxf(tmax, __shfl_xor(tmax, 4));

    const float mn = fmaxf(m, tmax);
    const float cr = expf(m - mn);
    float p[8];
    float tsum = 0.f;
#pragma unroll
    for (int jj = 0; jj < 8; ++jj) {
      p[jj] = expf(s[jj] - mn);
      tsum += p[jj];
    }
    tsum += __shfl_xor(tsum, 1);
    tsum += __shfl_xor(tsum, 2);
    tsum += __shfl_xor(tsum, 4);
    l = l * cr + tsum;
    m = mn;
#pragma unroll
    for (int i = 0; i < 8; ++i) o[i] *= cr;
#pragma unroll
    for (int jj = 0; jj < 8; ++jj) sP[r][(sub << 3) + jj] = p[jj];
    __syncthreads();

    for (int j = 0; j < KT; ++j) {
      const float pj = sP[r][j];
      const float4 v0 = *(const float4*)&sV[j][sub << 3];
      const float4 v1 = *(const float4*)&sV[j][(sub << 3) + 4];
      o[0] += pj * v0.x; o[1] += pj * v0.y; o[2] += pj * v0.z; o[3] += pj * v0.w;
      o[4] += pj * v1.x; o[5] += pj * v1.y; o[6] += pj * v1.z; o[7] += pj * v1.w;
    }
  }

  const float inv = 1.0f / l;
  const size_t off = (rowbase + qt * QT + r) * D_ + col0 + (sub << 3);
  float res[8];
#pragma unroll
  for (int i = 0; i < 8; ++i) res[i] = o[i] * inv;
  if (addend != nullptr) {
    float af[8];
    unpack8(*(const uint4*)(addend + off), af);
#pragma unroll
    for (int i = 0; i < 8; ++i) res[i] += af[i];
  }
  unsigned int w[4];
#pragma unroll
  for (int i = 0; i < 4; ++i)
    w[i] = (unsigned int)f2bf(res[2 * i]) | ((unsigned int)f2bf(res[2 * i + 1]) << 16);
  *(uint4*)(O + off) = make_uint4(w[0], w[1], w[2], w[3]);
}

// ---------------------------------------------------------------------------
// Host-side orchestration
// ---------------------------------------------------------------------------
extern "C" void kernel_launch(void* const* d_in, const int* in_sizes, int n_in,
                              void* d_out, int out_size, void* d_ws, size_t ws_size,
                              hipStream_t stream) {
  const float* gf = (const float*)d_in[0];
  const float* lf = (const float*)d_in[1];
  const float* tf = (const float*)d_in[2];
  const float* ge_w  = (const float*)d_in[3],  *ge_b  = (const float*)d_in[4];
  const float* le1_w = (const float*)d_in[5],  *le1_b = (const float*)d_in[6];
  const float* le2_w = (const float*)d_in[7],  *le2_b = (const float*)d_in[8];
  const float* qg_w  = (const float*)d_in[9],  *qg_b  = (const float*)d_in[10];
  const float* kg_w  = (const float*)d_in[11], *kg_b  = (const float*)d_in[12];
  const float* vg_w  = (const float*)d_in[13], *vg_b  = (const float*)d_in[14];
  const float* qp_w  = (const float*)d_in[15], *qp_b  = (const float*)d_in[16];
  const float* kp_w  = (const float*)d_in[17], *kp_b  = (const float*)d_in[18];
  const float* vp_w  = (const float*)d_in[19], *vp_b  = (const float*)d_in[20];
  const float* dense_w = (const float*)d_in[21], *dense_b = (const float*)d_in[22];
  const float* ml_w  = (const float*)d_in[23], *ml_b  = (const float*)d_in[24];
  const float* fc1_w = (const float*)d_in[25], *fc1_b = (const float*)d_in[26];
  const float* fc2_w = (const float*)d_in[27], *fc2_b = (const float*)d_in[28];

  float* out = (float*)d_out;

  // -------- workspace carve-up (bf16 buffers; ~198 MB total) --------
  char* p = (char*)d_ws;
  auto take = [&](size_t bytes) { char* r = p; p += (bytes + 255) & ~(size_t)255; return r; };
  const size_t WD  = (size_t)D_ * D_;        // 1M elems
  const size_t WF  = (size_t)DFF_ * D_;      // 4M elems
  const size_t ACT = (size_t)M_ * D_;        // 4M elems
  const size_t HB  = (size_t)M_ * DFF_;      // 16M elems

  unsigned short* wge    = (unsigned short*)take(WD * 2);
  unsigned short* wle1   = (unsigned short*)take(WD * 2);
  unsigned short* wle2   = (unsigned short*)take(WD * 2);
  unsigned short* wqg    = (unsigned short*)take(WD * 2);
  unsigned short* wkg    = (unsigned short*)take(WD * 2);
  unsigned short* wvg    = (unsigned short*)take(WD * 2);
  unsigned short* wqp    = (unsigned short*)take(WD * 2);
  unsigned short* wkp    = (unsigned short*)take(WD * 2);
  unsigned short* wvp    = (unsigned short*)take(WD * 2);
  unsigned short* wdense = (unsigned short*)take(WD * 2);
  unsigned short* wml    = (unsigned short*)take(WD * 2);
  unsigned short* wfc1   = (unsigned short*)take(WF * 2);
  unsigned short* wfc2   = (unsigned short*)take(WF * 2);
  unsigned short* gfb    = (unsigned short*)take(ACT * 2);
  unsigned short* lfb    = (unsigned short*)take(ACT * 2);
  unsigned short* tfb    = (unsigned short*)take(ACT * 2);
  unsigned short* glob   = (unsigned short*)take(ACT * 2);
  unsigned short* loc    = (unsigned short*)take(ACT * 2);
  unsigned short* dup    = (unsigned short*)take(ACT * 2);
  unsigned short* qgb    = (unsigned short*)take(ACT * 2);
  unsigned short* kgb    = (unsigned short*)take(ACT * 2);
  unsigned short* vgb    = (unsigned short*)take(ACT * 2);
  unsigned short* qpb    = (unsigned short*)take(ACT * 2);
  unsigned short* kpb    = (unsigned short*)take(ACT * 2);
  unsigned short* vpb    = (unsigned short*)take(ACT * 2);
  unsigned short* ub     = (unsigned short*)take(ACT * 2);
  unsigned short* lastb  = (unsigned short*)take(ACT * 2);
  unsigned short* out1   = (unsigned short*)take(ACT * 2);
  unsigned short* hbuf   = (unsigned short*)take(HB * 2);
  unsigned short* out2   = (unsigned short*)take(ACT * 2);

  // -------- conversions: 13 weights + 3 inputs, one launch --------
  CvtB cb;
  const float* srcs[NCVT] = {ge_w, le1_w, le2_w, qg_w, kg_w, vg_w, qp_w, kp_w, vp_w,
                             dense_w, ml_w, fc1_w, fc2_w, gf, lf, tf};
  unsigned short* dsts[NCVT] = {wge, wle1, wle2, wqg, wkg, wvg, wqp, wkp, wvp,
                                wdense, wml, wfc1, wfc2, gfb, lfb, tfb};
  const int lens[NCVT] = {(int)WD,(int)WD,(int)WD,(int)WD,(int)WD,(int)WD,(int)WD,(int)WD,(int)WD,
                          (int)WD,(int)WD,(int)WF,(int)WF,(int)ACT,(int)ACT,(int)ACT};
  for (int i = 0; i < NCVT; ++i) { cb.s[i] = srcs[i]; cb.d[i] = dsts[i]; cb.n[i] = lens[i]; }
  hipLaunchKernelGGL(cvt_k, dim3(512, NCVT), dim3(256), 0, stream, cb);

  const dim3 blk(256);
  auto mkb = [](std::initializer_list<const unsigned short*> As,
                std::initializer_list<const unsigned short*> Ws,
                std::initializer_list<const float*> Bs,
                std::initializer_list<void*> Ys) {
    GemmB g{};
    int i = 0;
    auto a = As.begin(); auto w = Ws.begin(); auto b = Bs.begin(); auto y = Ys.begin();
    for (; a != As.end(); ++a, ++w, ++b, ++y, ++i) { g.A[i] = *a; g.W[i] = *w; g.bias[i] = *b; g.Y[i] = *y; }
    return g;
  };

  // stage 1: embeddings (3 independent GEMMs, one launch)
  GemmB s1 = mkb({gfb, lfb, lfb}, {wge, wle1, wle2}, {ge_b, le1_b, le2_b},
                 {glob, dup, loc});
  hipLaunchKernelGGL((mgemm<0,0>), dim3(D_/128, M_/128, 3), blk, 0, stream, s1, M_, D_, D_);

  // stage 2: QKV projections (6 independent GEMMs, one launch)
  GemmB s2 = mkb({glob, loc, loc, dup, tfb, tfb}, {wqg, wkg, wvg, wqp, wkp, wvp},
                 {qg_b, kg_b, vg_b, qp_b, kp_b, vp_b}, {qgb, kgb, vgb, qpb, kpb, vpb});
  hipLaunchKernelGGL((mgemm<0,0>), dim3(D_/128, M_/128, 6), blk, 0, stream, s2, M_, D_, D_);

  // attention (bridge collapsed by associativity):
  //   u    = vg + softmax(qp kp^T / 8) @ vp
  //   last = softmax(qg kg^T / 8) @ u
  const int attnGrid = B_ * H_ * (S_ / 32);
  hipLaunchKernelGGL(attn_k, dim3(attnGrid), blk, 0, stream, qpb, kpb, vpb, vgb, ub);
  hipLaunchKernelGGL(attn_k, dim3(attnGrid), blk, 0, stream, qgb, kgb, ub,
                     (const unsigned short*)nullptr, lastb);

  // tail: dense -> fc1(GELU) -> fc2 -> ml
  GemmB gd = mkb({lastb}, {wdense}, {dense_b}, {out1});
  hipLaunchKernelGGL((mgemm<0,0>), dim3(D_/128, M_/128, 1), blk, 0, stream, gd, M_, D_, D_);
  GemmB g1 = mkb({out1}, {wfc1}, {fc1_b}, {hbuf});
  hipLaunchKernelGGL((mgemm<1,0>), dim3(DFF_/128, M_/128, 1), blk, 0, stream, g1, M_, DFF_, D_);
  GemmB g2 = mkb({hbuf}, {wfc2}, {fc2_b}, {out2});
  hipLaunchKernelGGL((mgemm<0,0>), dim3(D_/128, M_/128, 1), blk, 0, stream, g2, M_, D_, DFF_);
  GemmB gm = mkb({out2}, {wml}, {ml_b}, {out});
  hipLaunchKernelGGL((mgemm<0,1>), dim3(D_/128, M_/128, 1), blk, 0, stream, gm, M_, D_, D_);
}

// Round 6
// 653.639 us; speedup vs baseline: 5.3817x; 2.3695x over previous
//
#include <hip/hip_runtime.h>
#include <cstdint>
#include <cstddef>

// Problem constants
#define B_   4
#define S_   1024
#define D_   1024
#define H_   16
#define DH_  64
#define DFF_ 4096
#define M_   (B_ * S_)   // 4096 rows for all linears

typedef __bf16 bf16x8 __attribute__((ext_vector_type(8)));
typedef float  f32x4  __attribute__((ext_vector_type(4)));

__device__ __forceinline__ unsigned short f2bf(float f) {
  unsigned int u = __float_as_uint(f);
  u = (u + 0x7fffu + ((u >> 16) & 1u)) >> 16;   // round-to-nearest-even
  return (unsigned short)u;
}

__device__ __forceinline__ float bf2f(unsigned short h) {
  return __uint_as_float(((unsigned int)h) << 16);
}

// async global->LDS: lds dest is WAVE-UNIFORM base; HW adds lane*16 (m104)
__device__ __forceinline__ void gload_lds16(const void* g, void* l) {
  __builtin_amdgcn_global_load_lds((const __attribute__((address_space(1))) void*)g,
                                   (__attribute__((address_space(3))) void*)l, 16, 0, 0);
}

// ---------------------------------------------------------------------------
// Fused f32 -> bf16 conversion for up to 16 tensors in one launch
// ---------------------------------------------------------------------------
#define NCVT 16
struct CvtB { const float* s[NCVT]; unsigned short* d[NCVT]; int n[NCVT]; };

__global__ __launch_bounds__(256)
void cvt_k(CvtB cb) {
  const int z = blockIdx.y;
  const float* __restrict__ s = cb.s[z];
  unsigned short* __restrict__ d = cb.d[z];
  const int n = cb.n[z];
  const int stride = gridDim.x * 256 * 4;
  for (int i = (blockIdx.x * 256 + threadIdx.x) * 4; i < n; i += stride) {
    const float4 v = *(const float4*)(s + i);
    const unsigned int a = (unsigned int)f2bf(v.x) | ((unsigned int)f2bf(v.y) << 16);
    const unsigned int b = (unsigned int)f2bf(v.z) | ((unsigned int)f2bf(v.w) << 16);
    *(uint2*)(d + i) = make_uint2(a, b);
  }
}

// ---------------------------------------------------------------------------
// Batched MFMA GEMM (unchanged from passing round-5 kernel)
// ---------------------------------------------------------------------------
#define MAXB 6
struct GemmB {
  const unsigned short* A[MAXB];
  const unsigned short* W[MAXB];
  const float*          bias[MAXB];
  void*                 Y[MAXB];
};

template <int GELU, int OUTF32>
__global__ __launch_bounds__(256)
void mgemm(GemmB gb, int M, int N, int K) {
  __shared__ unsigned short sA[128][32];
  __shared__ unsigned short sB[128][32];

  const int z = blockIdx.z;
  const unsigned short* __restrict__ A = gb.A[z];
  const unsigned short* __restrict__ W = gb.W[z];
  const float* __restrict__ bias = gb.bias[z];

  const int t  = threadIdx.x;
  const int ln = t & 63;
  const int wv = t >> 6;
  const int wr = wv >> 1;
  const int wc = wv & 1;
  const int m0 = blockIdx.y * 128;
  const int n0 = blockIdx.x * 128;

  const int srow  = ln >> 2;
  const int skoff = (ln & 3) << 3;

  f32x4 acc[4][4] = {};

  char* sAb = (char*)&sA[0][0];
  char* sBb = (char*)&sB[0][0];

  for (int k0 = 0; k0 < K; k0 += 32) {
    __syncthreads();
#pragma unroll
    for (int i = 0; i < 2; ++i) {
      const int c = (wv << 1) | i;
      gload_lds16(A + (size_t)(m0 + (c << 4) + srow) * K + k0 + skoff, sAb + (c << 10));
      gload_lds16(W + (size_t)(n0 + (c << 4) + srow) * K + k0 + skoff, sBb + (c << 10));
    }
    __syncthreads();

    const int rsel = ln & 15;
    const int csel = (ln >> 4) << 4;
    bf16x8 av[4], bv[4];
#pragma unroll
    for (int m = 0; m < 4; ++m)
      av[m] = *(const bf16x8*)(sAb + (((wr << 6) + (m << 4) + rsel) << 6) + csel);
#pragma unroll
    for (int n = 0; n < 4; ++n)
      bv[n] = *(const bf16x8*)(sBb + (((wc << 6) + (n << 4) + rsel) << 6) + csel);

#pragma unroll
    for (int m = 0; m < 4; ++m)
#pragma unroll
      for (int n = 0; n < 4; ++n)
        acc[m][n] = __builtin_amdgcn_mfma_f32_16x16x32_bf16(av[m], bv[n], acc[m][n], 0, 0, 0);
  }

  const int rbase = m0 + (wr << 6) + ((ln >> 4) << 2);
  const int cb0   = n0 + (wc << 6) + (ln & 15);
#pragma unroll
  for (int m = 0; m < 4; ++m) {
#pragma unroll
    for (int n = 0; n < 4; ++n) {
      const int col = cb0 + (n << 4);
      const float bi = bias[col];
#pragma unroll
      for (int j = 0; j < 4; ++j) {
        const int row = rbase + (m << 4) + j;
        float x = acc[m][n][j] + bi;
        if (GELU) x = 0.5f * x * (1.0f + erff(x * 0.70710678118654752f));
        if (OUTF32) ((float*)gb.Y[z])[(size_t)row * N + col] = x;
        else        ((unsigned short*)gb.Y[z])[(size_t)row * N + col] = f2bf(x);
      }
    }
  }
}

// ---------------------------------------------------------------------------
// Per-head V transpose: V[b*S+kv][h*64+d] -> Vt[bh][d][kv]
// Coalesced: 64 lanes read contiguous 128 B per kv row; 16 B store per thread.
// grid (32, 64) x 256 threads.
// ---------------------------------------------------------------------------
__global__ __launch_bounds__(256)
void vtrans_k(const unsigned short* __restrict__ V, unsigned short* __restrict__ Vt) {
  const int t   = threadIdx.x;
  const int d   = t & 63;
  const int sub = t >> 6;
  const int bh  = blockIdx.y;
  const int b   = bh >> 4;
  const int col0 = (bh & 15) * DH_;
  const int kv0 = blockIdx.x * 32 + sub * 8;
  unsigned short tmp[8];
#pragma unroll
  for (int i = 0; i < 8; ++i)
    tmp[i] = V[((size_t)b * S_ + kv0 + i) * D_ + col0 + d];
  *(uint4*)(Vt + ((size_t)bh * DH_ + d) * S_ + kv0) = *(const uint4*)tmp;
}

// ---------------------------------------------------------------------------
// MFMA flash attention: O = softmax(Q K^T / 8) @ V (+ addend), per (b,h).
// Block = (q-tile of 64 rows, bh); 4 waves x 16 q-rows; KT=64 kv per step.
// Fragments: A(row=l&15, k=(l>>4)*8..+7), B(col-row=l&15, same k),
// C/D(col=l&15, row=(l>>4)*4+reg) -- layouts verified by the passing mgemm.
// Q/K/Vt tiles: linear LDS dest + XOR source-chunk swizzle (chunk^row&7)
// -> conflict-free b128 fragment reads (G4/T2, m173 pattern).
// P roundtrip through per-wave LDS [16][72] bf16 (pad -> 2-way = free).
// ---------------------------------------------------------------------------
__global__ __launch_bounds__(256)
void attn_mfma_k(const unsigned short* __restrict__ Q,
                 const unsigned short* __restrict__ K,
                 const unsigned short* __restrict__ Vt,
                 const unsigned short* __restrict__ addend,
                 unsigned short* __restrict__ O) {
  __shared__ unsigned short sQ[64 * 64];
  __shared__ unsigned short sK[64 * 64];
  __shared__ unsigned short sV[64 * 64];
  __shared__ unsigned short sP[4][16 * 72];

  const int t  = threadIdx.x;
  const int l  = t & 63;
  const int w  = t >> 6;
  const int bh = blockIdx.y;
  const int b  = bh >> 4;
  const size_t rowQ = (size_t)b * S_ + blockIdx.x * 64;
  const size_t rowK = (size_t)b * S_;
  const int col0 = (bh & 15) * DH_;

  const int lr8 = l >> 3;             // row-within-8 for staging
  const int lsw = (l & 7) ^ lr8;      // pre-swizzled source chunk
  char* sQb = (char*)sQ;
  char* sKb = (char*)sK;
  char* sVb = (char*)sV;

  // stage Q (once) + K/Vt tile 0. Dest is wave-uniform; HW adds lane*16.
#pragma unroll
  for (int i = 0; i < 2; ++i) {
    const int r = w * 16 + i * 8 + lr8;
    gload_lds16(Q + (rowQ + r) * D_ + col0 + lsw * 8, sQb + w * 2048 + i * 1024);
    gload_lds16(K + (rowK + r) * D_ + col0 + lsw * 8, sKb + w * 2048 + i * 1024);
    gload_lds16(Vt + ((size_t)bh * DH_ + r) * S_ + lsw * 8, sVb + w * 2048 + i * 1024);
  }
  __syncthreads();

  // hoisted Q A-fragments (this wave's 16 q-rows)
  bf16x8 qa[2];
#pragma unroll
  for (int c = 0; c < 2; ++c)
    qa[c] = *(const bf16x8*)(sQb + (w * 16 + (l & 15)) * 128 +
                             ((((c << 2) + (l >> 4)) ^ (l & 7)) << 4));

  f32x4 o[4] = {};
  float mrow[4] = {-1e30f, -1e30f, -1e30f, -1e30f};
  float lrow[4] = {0.f, 0.f, 0.f, 0.f};

  char* sPw = (char*)(sP[w]);

  for (int kt = 0; kt < S_ / 64; ++kt) {
    // ---- QK^T: S[q][kv] for 4 kv-16-tiles ----
    f32x4 s[4];
#pragma unroll
    for (int n = 0; n < 4; ++n) {
      f32x4 z = {};
#pragma unroll
      for (int c = 0; c < 2; ++c) {
        const bf16x8 kb = *(const bf16x8*)(sKb + (n * 16 + (l & 15)) * 128 +
                              ((((c << 2) + (l >> 4)) ^ (l & 7)) << 4));
        z = __builtin_amdgcn_mfma_f32_16x16x32_bf16(qa[c], kb, z, 0, 0, 0);
      }
      s[n] = z;
    }

    // ---- online softmax: lane owns rows q=(l>>4)*4+j, cols kv=n*16+(l&15) ----
#pragma unroll
    for (int j = 0; j < 4; ++j) {
      float rm = fmaxf(fmaxf(s[0][j], s[1][j]), fmaxf(s[2][j], s[3][j]));
      rm = fmaxf(rm, __shfl_xor(rm, 1));
      rm = fmaxf(rm, __shfl_xor(rm, 2));
      rm = fmaxf(rm, __shfl_xor(rm, 4));
      rm = fmaxf(rm, __shfl_xor(rm, 8));
      const float mn = fmaxf(mrow[j], rm * 0.125f);
      const float cr = __expf(mrow[j] - mn);
      mrow[j] = mn;
      float rs = 0.f;
#pragma unroll
      for (int n = 0; n < 4; ++n) {
        const float p = __expf(s[n][j] * 0.125f - mn);
        rs += p;
        ((unsigned short*)sPw)[((l >> 4) * 4 + j) * 72 + n * 16 + (l & 15)] = f2bf(p);
      }
      rs += __shfl_xor(rs, 1);
      rs += __shfl_xor(rs, 2);
      rs += __shfl_xor(rs, 4);
      rs += __shfl_xor(rs, 8);
      lrow[j] = lrow[j] * cr + rs;
#pragma unroll
      for (int n2 = 0; n2 < 4; ++n2) o[n2][j] *= cr;
    }

    // ---- P @ V: A from sP, B from transposed-V tile ----
    bf16x8 pa[2];
#pragma unroll
    for (int kc = 0; kc < 2; ++kc)
      pa[kc] = *(const bf16x8*)(sPw + (l & 15) * 144 + kc * 64 + (l >> 4) * 16);
#pragma unroll
    for (int n2 = 0; n2 < 4; ++n2) {
#pragma unroll
      for (int kc = 0; kc < 2; ++kc) {
        const bf16x8 vb = *(const bf16x8*)(sVb + (n2 * 16 + (l & 15)) * 128 +
                               ((((kc << 2) + (l >> 4)) ^ (l & 7)) << 4));
        o[n2] = __builtin_amdgcn_mfma_f32_16x16x32_bf16(pa[kc], vb, o[n2], 0, 0, 0);
      }
    }

    __syncthreads();   // all waves done reading sK/sV
    if (kt + 1 < S_ / 64) {
#pragma unroll
      for (int i = 0; i < 2; ++i) {
        const int r = w * 16 + i * 8 + lr8;
        gload_lds16(K + (rowK + (size_t)(kt + 1) * 64 + r) * D_ + col0 + lsw * 8,
                    sKb + w * 2048 + i * 1024);
        gload_lds16(Vt + ((size_t)bh * DH_ + r) * S_ + (kt + 1) * 64 + lsw * 8,
                    sVb + w * 2048 + i * 1024);
      }
    }
    __syncthreads();   // vmcnt drained -> tiles ready
  }

  // ---- epilogue ----
  float inv[4];
#pragma unroll
  for (int j = 0; j < 4; ++j) inv[j] = 1.f / lrow[j];
#pragma unroll
  for (int n2 = 0; n2 < 4; ++n2) {
#pragma unroll
    for (int j = 0; j < 4; ++j) {
      const size_t row = rowQ + w * 16 + (l >> 4) * 4 + j;
      const int col = col0 + n2 * 16 + (l & 15);
      float x = o[n2][j] * inv[j];
      if (addend != nullptr) x += bf2f(addend[row * D_ + col]);
      O[row * D_ + col] = f2bf(x);
    }
  }
}

// ---------------------------------------------------------------------------
// Host-side orchestration
// ---------------------------------------------------------------------------
extern "C" void kernel_launch(void* const* d_in, const int* in_sizes, int n_in,
                              void* d_out, int out_size, void* d_ws, size_t ws_size,
                              hipStream_t stream) {
  const float* gf = (const float*)d_in[0];
  const float* lf = (const float*)d_in[1];
  const float* tf = (const float*)d_in[2];
  const float* ge_w  = (const float*)d_in[3],  *ge_b  = (const float*)d_in[4];
  const float* le1_w = (const float*)d_in[5],  *le1_b = (const float*)d_in[6];
  const float* le2_w = (const float*)d_in[7],  *le2_b = (const float*)d_in[8];
  const float* qg_w  = (const float*)d_in[9],  *qg_b  = (const float*)d_in[10];
  const float* kg_w  = (const float*)d_in[11], *kg_b  = (const float*)d_in[12];
  const float* vg_w  = (const float*)d_in[13], *vg_b  = (const float*)d_in[14];
  const float* qp_w  = (const float*)d_in[15], *qp_b  = (const float*)d_in[16];
  const float* kp_w  = (const float*)d_in[17], *kp_b  = (const float*)d_in[18];
  const float* vp_w  = (const float*)d_in[19], *vp_b  = (const float*)d_in[20];
  const float* dense_w = (const float*)d_in[21], *dense_b = (const float*)d_in[22];
  const float* ml_w  = (const float*)d_in[23], *ml_b  = (const float*)d_in[24];
  const float* fc1_w = (const float*)d_in[25], *fc1_b = (const float*)d_in[26];
  const float* fc2_w = (const float*)d_in[27], *fc2_b = (const float*)d_in[28];

  float* out = (float*)d_out;

  // -------- workspace carve-up (bf16 buffers; ~198 MB total) --------
  char* p = (char*)d_ws;
  auto take = [&](size_t bytes) { char* r = p; p += (bytes + 255) & ~(size_t)255; return r; };
  const size_t WD  = (size_t)D_ * D_;
  const size_t WF  = (size_t)DFF_ * D_;
  const size_t ACT = (size_t)M_ * D_;
  const size_t HB  = (size_t)M_ * DFF_;

  unsigned short* wge    = (unsigned short*)take(WD * 2);
  unsigned short* wle1   = (unsigned short*)take(WD * 2);
  unsigned short* wle2   = (unsigned short*)take(WD * 2);
  unsigned short* wqg    = (unsigned short*)take(WD * 2);
  unsigned short* wkg    = (unsigned short*)take(WD * 2);
  unsigned short* wvg    = (unsigned short*)take(WD * 2);
  unsigned short* wqp    = (unsigned short*)take(WD * 2);
  unsigned short* wkp    = (unsigned short*)take(WD * 2);
  unsigned short* wvp    = (unsigned short*)take(WD * 2);
  unsigned short* wdense = (unsigned short*)take(WD * 2);
  unsigned short* wml    = (unsigned short*)take(WD * 2);
  unsigned short* wfc1   = (unsigned short*)take(WF * 2);
  unsigned short* wfc2   = (unsigned short*)take(WF * 2);
  unsigned short* gfb    = (unsigned short*)take(ACT * 2);
  unsigned short* lfb    = (unsigned short*)take(ACT * 2);
  unsigned short* tfb    = (unsigned short*)take(ACT * 2);
  unsigned short* glob   = (unsigned short*)take(ACT * 2);
  unsigned short* loc    = (unsigned short*)take(ACT * 2);
  unsigned short* dup    = (unsigned short*)take(ACT * 2);
  unsigned short* qgb    = (unsigned short*)take(ACT * 2);
  unsigned short* kgb    = (unsigned short*)take(ACT * 2);
  unsigned short* vgb    = (unsigned short*)take(ACT * 2);
  unsigned short* qpb    = (unsigned short*)take(ACT * 2);
  unsigned short* kpb    = (unsigned short*)take(ACT * 2);
  unsigned short* vpb    = (unsigned short*)take(ACT * 2);
  unsigned short* ub     = (unsigned short*)take(ACT * 2);
  unsigned short* lastb  = (unsigned short*)take(ACT * 2);
  unsigned short* out1   = (unsigned short*)take(ACT * 2);
  unsigned short* hbuf   = (unsigned short*)take(HB * 2);
  unsigned short* out2   = (unsigned short*)take(ACT * 2);

  // transposed-V buffers reuse slots dead after the GEMM stages
  unsigned short* vt1 = gfb;   // gfb only read by stage-1
  unsigned short* vtu = lfb;   // lfb only read by stage-1

  // -------- conversions: 13 weights + 3 inputs, one launch --------
  CvtB cb;
  const float* srcs[NCVT] = {ge_w, le1_w, le2_w, qg_w, kg_w, vg_w, qp_w, kp_w, vp_w,
                             dense_w, ml_w, fc1_w, fc2_w, gf, lf, tf};
  unsigned short* dsts[NCVT] = {wge, wle1, wle2, wqg, wkg, wvg, wqp, wkp, wvp,
                                wdense, wml, wfc1, wfc2, gfb, lfb, tfb};
  const int lens[NCVT] = {(int)WD,(int)WD,(int)WD,(int)WD,(int)WD,(int)WD,(int)WD,(int)WD,(int)WD,
                          (int)WD,(int)WD,(int)WF,(int)WF,(int)ACT,(int)ACT,(int)ACT};
  for (int i = 0; i < NCVT; ++i) { cb.s[i] = srcs[i]; cb.d[i] = dsts[i]; cb.n[i] = lens[i]; }
  hipLaunchKernelGGL(cvt_k, dim3(512, NCVT), dim3(256), 0, stream, cb);

  const dim3 blk(256);
  auto mkb = [](std::initializer_list<const unsigned short*> As,
                std::initializer_list<const unsigned short*> Ws,
                std::initializer_list<const float*> Bs,
                std::initializer_list<void*> Ys) {
    GemmB g{};
    int i = 0;
    auto a = As.begin(); auto w = Ws.begin(); auto b = Bs.begin(); auto y = Ys.begin();
    for (; a != As.end(); ++a, ++w, ++b, ++y, ++i) { g.A[i] = *a; g.W[i] = *w; g.bias[i] = *b; g.Y[i] = *y; }
    return g;
  };

  // stage 1: embeddings
  GemmB s1 = mkb({gfb, lfb, lfb}, {wge, wle1, wle2}, {ge_b, le1_b, le2_b},
                 {glob, dup, loc});
  hipLaunchKernelGGL((mgemm<0,0>), dim3(D_/128, M_/128, 3), blk, 0, stream, s1, M_, D_, D_);

  // stage 2: QKV projections
  GemmB s2 = mkb({glob, loc, loc, dup, tfb, tfb}, {wqg, wkg, wvg, wqp, wkp, wvp},
                 {qg_b, kg_b, vg_b, qp_b, kp_b, vp_b}, {qgb, kgb, vgb, qpb, kpb, vpb});
  hipLaunchKernelGGL((mgemm<0,0>), dim3(D_/128, M_/128, 6), blk, 0, stream, s2, M_, D_, D_);

  // attention (bridge collapsed by associativity):
  //   u    = vg + softmax(qp kp^T / 8) @ vp
  //   last = softmax(qg kg^T / 8) @ u
  hipLaunchKernelGGL(vtrans_k, dim3(32, 64), blk, 0, stream, vpb, vt1);
  hipLaunchKernelGGL(attn_mfma_k, dim3(16, 64), blk, 0, stream, qpb, kpb, vt1, vgb, ub);
  hipLaunchKernelGGL(vtrans_k, dim3(32, 64), blk, 0, stream, ub, vtu);
  hipLaunchKernelGGL(attn_mfma_k, dim3(16, 64), blk, 0, stream, qgb, kgb, vtu,
                     (const unsigned short*)nullptr, lastb);

  // tail: dense -> fc1(GELU) -> fc2 -> ml
  GemmB gd = mkb({lastb}, {wdense}, {dense_b}, {out1});
  hipLaunchKernelGGL((mgemm<0,0>), dim3(D_/128, M_/128, 1), blk, 0, stream, gd, M_, D_, D_);
  GemmB g1 = mkb({out1}, {wfc1}, {fc1_b}, {hbuf});
  hipLaunchKernelGGL((mgemm<1,0>), dim3(DFF_/128, M_/128, 1), blk, 0, stream, g1, M_, DFF_, D_);
  GemmB g2 = mkb({hbuf}, {wfc2}, {fc2_b}, {out2});
  hipLaunchKernelGGL((mgemm<0,0>), dim3(D_/128, M_/128, 1), blk, 0, stream, g2, M_, D_, DFF_);
  GemmB gm = mkb({out2}, {wml}, {ml_b}, {out});
  hipLaunchKernelGGL((mgemm<0,1>), dim3(D_/128, M_/128, 1), blk, 0, stream, gm, M_, D_, D_);
}

// Round 8
// 599.423 us; speedup vs baseline: 5.8684x; 1.0904x over previous
//
#include <hip/hip_runtime.h>
#include <cstdint>
#include <cstddef>

// Problem constants
#define B_   4
#define S_   1024
#define D_   1024
#define H_   16
#define DH_  64
#define DFF_ 4096
#define M_   (B_ * S_)   // 4096 rows for all linears

typedef __bf16 bf16x8 __attribute__((ext_vector_type(8)));
typedef float  f32x4  __attribute__((ext_vector_type(4)));

__device__ __forceinline__ unsigned short f2bf(float f) {
  unsigned int u = __float_as_uint(f);
  u = (u + 0x7fffu + ((u >> 16) & 1u)) >> 16;   // round-to-nearest-even
  return (unsigned short)u;
}

__device__ __forceinline__ float bf2f(unsigned short h) {
  return __uint_as_float(((unsigned int)h) << 16);
}

// async global->LDS: lds dest is WAVE-UNIFORM base; HW adds lane*16 (m104)
__device__ __forceinline__ void gload_lds16(const void* g, void* l) {
  __builtin_amdgcn_global_load_lds((const __attribute__((address_space(1))) void*)g,
                                   (__attribute__((address_space(3))) void*)l, 16, 0, 0);
}

// ---------------------------------------------------------------------------
// Fused f32 -> bf16 conversion for up to 16 tensors in one launch
// ---------------------------------------------------------------------------
#define NCVT 16
struct CvtB { const float* s[NCVT]; unsigned short* d[NCVT]; int n[NCVT]; };

__global__ __launch_bounds__(256)
void cvt_k(CvtB cb) {
  const int z = blockIdx.y;
  const float* __restrict__ s = cb.s[z];
  unsigned short* __restrict__ d = cb.d[z];
  const int n = cb.n[z];
  const int stride = gridDim.x * 256 * 4;
  for (int i = (blockIdx.x * 256 + threadIdx.x) * 4; i < n; i += stride) {
    const float4 v = *(const float4*)(s + i);
    const unsigned int a = (unsigned int)f2bf(v.x) | ((unsigned int)f2bf(v.y) << 16);
    const unsigned int b = (unsigned int)f2bf(v.z) | ((unsigned int)f2bf(v.w) << 16);
    *(uint2*)(d + i) = make_uint2(a, b);
  }
}

// ---------------------------------------------------------------------------
// Batched MFMA GEMM: Y[M,N] = A[M,K] @ W[N,K]^T + bias  (bf16 in, f32 acc)
// Round-7 changes vs the passing round-6 kernel:
//  - double-buffered LDS prefetch (T3-minimum 2-phase): stage tile k+1
//    before computing tile k; ONE barrier per K-step (was two). K-loop
//    unrolled x2 so buffer refs are compile-time static (rule #20).
//  - bijective XCD-aware tile swizzle (T1/m204) on the (x,y) grid.
// ---------------------------------------------------------------------------
#define MAXB 6
struct GemmB {
  const unsigned short* A[MAXB];
  const unsigned short* W[MAXB];
  const float*          bias[MAXB];
  void*                 Y[MAXB];
};

template <int GELU, int OUTF32>
__global__ __launch_bounds__(256)
void mgemm(GemmB gb, int M, int N, int K) {
  __shared__ unsigned short sA0[128][32], sA1[128][32];   // 8 KB each
  __shared__ unsigned short sB0[128][32], sB1[128][32];

  const int z = blockIdx.z;
  const unsigned short* __restrict__ A = gb.A[z];
  const unsigned short* __restrict__ W = gb.W[z];
  const float* __restrict__ bias = gb.bias[z];

  const int t  = threadIdx.x;
  const int ln = t & 63;
  const int wv = t >> 6;
  const int wr = wv >> 1;
  const int wc = wv & 1;

  // bijective XCD swizzle (m204): each XCD gets a contiguous tile chunk
  const int gx   = gridDim.x;
  const int nwg  = gx * gridDim.y;
  const int orig = blockIdx.y * gx + blockIdx.x;
  const int q8   = nwg >> 3, r8 = nwg & 7;
  const int xcd  = orig & 7, idx = orig >> 3;
  const int wgid = (xcd < r8 ? xcd * (q8 + 1) : r8 * (q8 + 1) + (xcd - r8) * q8) + idx;
  const int m0 = (wgid / gx) * 128;
  const int n0 = (wgid % gx) * 128;

  const int srow  = ln >> 2;        // row within 16-row chunk
  const int skoff = (ln & 3) << 3;  // k offset (elements)

  f32x4 acc[4][4] = {};

  char* a0 = (char*)&sA0[0][0];  char* a1 = (char*)&sA1[0][0];
  char* b0 = (char*)&sB0[0][0];  char* b1 = (char*)&sB1[0][0];

  const int rsel = ln & 15;
  const int csel = (ln >> 4) << 4;

  // stage K-tile kt into (dstA,dstB): 2 chunks of 16 rows per wave, 16 B/lane
  auto stage = [&](int kt, char* dstA, char* dstB) {
    const int k0 = kt << 5;
#pragma unroll
    for (int i = 0; i < 2; ++i) {
      const int c = (wv << 1) | i;
      gload_lds16(A + (size_t)(m0 + (c << 4) + srow) * K + k0 + skoff, dstA + (c << 10));
      gload_lds16(W + (size_t)(n0 + (c << 4) + srow) * K + k0 + skoff, dstB + (c << 10));
    }
  };

  // fragment reads + 16 MFMA on one buffered tile
  auto compute = [&](const char* srcA, const char* srcB) {
    bf16x8 av[4], bv[4];
#pragma unroll
    for (int m = 0; m < 4; ++m)
      av[m] = *(const bf16x8*)(srcA + (((wr << 6) + (m << 4) + rsel) << 6) + csel);
#pragma unroll
    for (int n = 0; n < 4; ++n)
      bv[n] = *(const bf16x8*)(srcB + (((wc << 6) + (n << 4) + rsel) << 6) + csel);
#pragma unroll
    for (int m = 0; m < 4; ++m)
#pragma unroll
      for (int n = 0; n < 4; ++n)
        acc[m][n] = __builtin_amdgcn_mfma_f32_16x16x32_bf16(av[m], bv[n], acc[m][n], 0, 0, 0);
  };

  const int NK = K >> 5;   // always even (K = 1024 or 4096)
  stage(0, a0, b0);
  for (int kt = 0; kt < NK; kt += 2) {
    __syncthreads();                 // buf0 ready (vmcnt drained); buf1 free
    stage(kt + 1, a1, b1);           // prefetch overlaps compute(buf0)
    compute(a0, b0);
    __syncthreads();                 // buf1 ready; buf0 free
    if (kt + 2 < NK) stage(kt + 2, a0, b0);
    compute(a1, b1);
  }

  // epilogue: C/D layout col = lane&15, row = (lane>>4)*4 + reg
  const int rbase = m0 + (wr << 6) + ((ln >> 4) << 2);
  const int cb0   = n0 + (wc << 6) + (ln & 15);
#pragma unroll
  for (int m = 0; m < 4; ++m) {
#pragma unroll
    for (int n = 0; n < 4; ++n) {
      const int col = cb0 + (n << 4);
      const float bi = bias[col];
#pragma unroll
      for (int j = 0; j < 4; ++j) {
        const int row = rbase + (m << 4) + j;
        float x = acc[m][n][j] + bi;
        if (GELU) x = 0.5f * x * (1.0f + erff(x * 0.70710678118654752f));
        if (OUTF32) ((float*)gb.Y[z])[(size_t)row * N + col] = x;
        else        ((unsigned short*)gb.Y[z])[(size_t)row * N + col] = f2bf(x);
      }
    }
  }
}

// ---------------------------------------------------------------------------
// Per-head V transpose: V[b*S+kv][h*64+d] -> Vt[bh][d][kv]
// ---------------------------------------------------------------------------
__global__ __launch_bounds__(256)
void vtrans_k(const unsigned short* __restrict__ V, unsigned short* __restrict__ Vt) {
  const int t   = threadIdx.x;
  const int d   = t & 63;
  const int sub = t >> 6;
  const int bh  = blockIdx.y;
  const int b   = bh >> 4;
  const int col0 = (bh & 15) * DH_;
  const int kv0 = blockIdx.x * 32 + sub * 8;
  unsigned short tmp[8];
#pragma unroll
  for (int i = 0; i < 8; ++i)
    tmp[i] = V[((size_t)b * S_ + kv0 + i) * D_ + col0 + d];
  *(uint4*)(Vt + ((size_t)bh * DH_ + d) * S_ + kv0) = *(const uint4*)tmp;
}

// ---------------------------------------------------------------------------
// MFMA flash attention (unchanged from passing round-6 kernel)
// ---------------------------------------------------------------------------
__global__ __launch_bounds__(256)
void attn_mfma_k(const unsigned short* __restrict__ Q,
                 const unsigned short* __restrict__ K,
                 const unsigned short* __restrict__ Vt,
                 const unsigned short* __restrict__ addend,
                 unsigned short* __restrict__ O) {
  __shared__ unsigned short sQ[64 * 64];
  __shared__ unsigned short sK[64 * 64];
  __shared__ unsigned short sV[64 * 64];
  __shared__ unsigned short sP[4][16 * 72];

  const int t  = threadIdx.x;
  const int l  = t & 63;
  const int w  = t >> 6;
  const int bh = blockIdx.y;
  const int b  = bh >> 4;
  const size_t rowQ = (size_t)b * S_ + blockIdx.x * 64;
  const size_t rowK = (size_t)b * S_;
  const int col0 = (bh & 15) * DH_;

  const int lr8 = l >> 3;
  const int lsw = (l & 7) ^ lr8;
  char* sQb = (char*)sQ;
  char* sKb = (char*)sK;
  char* sVb = (char*)sV;

#pragma unroll
  for (int i = 0; i < 2; ++i) {
    const int r = w * 16 + i * 8 + lr8;
    gload_lds16(Q + (rowQ + r) * D_ + col0 + lsw * 8, sQb + w * 2048 + i * 1024);
    gload_lds16(K + (rowK + r) * D_ + col0 + lsw * 8, sKb + w * 2048 + i * 1024);
    gload_lds16(Vt + ((size_t)bh * DH_ + r) * S_ + lsw * 8, sVb + w * 2048 + i * 1024);
  }
  __syncthreads();

  bf16x8 qa[2];
#pragma unroll
  for (int c = 0; c < 2; ++c)
    qa[c] = *(const bf16x8*)(sQb + (w * 16 + (l & 15)) * 128 +
                             ((((c << 2) + (l >> 4)) ^ (l & 7)) << 4));

  f32x4 o[4] = {};
  float mrow[4] = {-1e30f, -1e30f, -1e30f, -1e30f};
  float lrow[4] = {0.f, 0.f, 0.f, 0.f};

  char* sPw = (char*)(sP[w]);

  for (int kt = 0; kt < S_ / 64; ++kt) {
    f32x4 s[4];
#pragma unroll
    for (int n = 0; n < 4; ++n) {
      f32x4 z = {};
#pragma unroll
      for (int c = 0; c < 2; ++c) {
        const bf16x8 kb = *(const bf16x8*)(sKb + (n * 16 + (l & 15)) * 128 +
                              ((((c << 2) + (l >> 4)) ^ (l & 7)) << 4));
        z = __builtin_amdgcn_mfma_f32_16x16x32_bf16(qa[c], kb, z, 0, 0, 0);
      }
      s[n] = z;
    }

#pragma unroll
    for (int j = 0; j < 4; ++j) {
      float rm = fmaxf(fmaxf(s[0][j], s[1][j]), fmaxf(s[2][j], s[3][j]));
      rm = fmaxf(rm, __shfl_xor(rm, 1));
      rm = fmaxf(rm, __shfl_xor(rm, 2));
      rm = fmaxf(rm, __shfl_xor(rm, 4));
      rm = fmaxf(rm, __shfl_xor(rm, 8));
      const float mn = fmaxf(mrow[j], rm * 0.125f);
      const float cr = __expf(mrow[j] - mn);
      mrow[j] = mn;
      float rs = 0.f;
#pragma unroll
      for (int n = 0; n < 4; ++n) {
        const float p = __expf(s[n][j] * 0.125f - mn);
        rs += p;
        ((unsigned short*)sPw)[((l >> 4) * 4 + j) * 72 + n * 16 + (l & 15)] = f2bf(p);
      }
      rs += __shfl_xor(rs, 1);
      rs += __shfl_xor(rs, 2);
      rs += __shfl_xor(rs, 4);
      rs += __shfl_xor(rs, 8);
      lrow[j] = lrow[j] * cr + rs;
#pragma unroll
      for (int n2 = 0; n2 < 4; ++n2) o[n2][j] *= cr;
    }

    bf16x8 pa[2];
#pragma unroll
    for (int kc = 0; kc < 2; ++kc)
      pa[kc] = *(const bf16x8*)(sPw + (l & 15) * 144 + kc * 64 + (l >> 4) * 16);
#pragma unroll
    for (int n2 = 0; n2 < 4; ++n2) {
#pragma unroll
      for (int kc = 0; kc < 2; ++kc) {
        const bf16x8 vb = *(const bf16x8*)(sVb + (n2 * 16 + (l & 15)) * 128 +
                               ((((kc << 2) + (l >> 4)) ^ (l & 7)) << 4));
        o[n2] = __builtin_amdgcn_mfma_f32_16x16x32_bf16(pa[kc], vb, o[n2], 0, 0, 0);
      }
    }

    __syncthreads();
    if (kt + 1 < S_ / 64) {
#pragma unroll
      for (int i = 0; i < 2; ++i) {
        const int r = w * 16 + i * 8 + lr8;
        gload_lds16(K + (rowK + (size_t)(kt + 1) * 64 + r) * D_ + col0 + lsw * 8,
                    sKb + w * 2048 + i * 1024);
        gload_lds16(Vt + ((size_t)bh * DH_ + r) * S_ + (kt + 1) * 64 + lsw * 8,
                    sVb + w * 2048 + i * 1024);
      }
    }
    __syncthreads();
  }

  float inv[4];
#pragma unroll
  for (int j = 0; j < 4; ++j) inv[j] = 1.f / lrow[j];
#pragma unroll
  for (int n2 = 0; n2 < 4; ++n2) {
#pragma unroll
    for (int j = 0; j < 4; ++j) {
      const size_t row = rowQ + w * 16 + (l >> 4) * 4 + j;
      const int col = col0 + n2 * 16 + (l & 15);
      float x = o[n2][j] * inv[j];
      if (addend != nullptr) x += bf2f(addend[row * D_ + col]);
      O[row * D_ + col] = f2bf(x);
    }
  }
}

// ---------------------------------------------------------------------------
// Host-side orchestration
// ---------------------------------------------------------------------------
extern "C" void kernel_launch(void* const* d_in, const int* in_sizes, int n_in,
                              void* d_out, int out_size, void* d_ws, size_t ws_size,
                              hipStream_t stream) {
  const float* gf = (const float*)d_in[0];
  const float* lf = (const float*)d_in[1];
  const float* tf = (const float*)d_in[2];
  const float* ge_w  = (const float*)d_in[3],  *ge_b  = (const float*)d_in[4];
  const float* le1_w = (const float*)d_in[5],  *le1_b = (const float*)d_in[6];
  const float* le2_w = (const float*)d_in[7],  *le2_b = (const float*)d_in[8];
  const float* qg_w  = (const float*)d_in[9],  *qg_b  = (const float*)d_in[10];
  const float* kg_w  = (const float*)d_in[11], *kg_b  = (const float*)d_in[12];
  const float* vg_w  = (const float*)d_in[13], *vg_b  = (const float*)d_in[14];
  const float* qp_w  = (const float*)d_in[15], *qp_b  = (const float*)d_in[16];
  const float* kp_w  = (const float*)d_in[17], *kp_b  = (const float*)d_in[18];
  const float* vp_w  = (const float*)d_in[19], *vp_b  = (const float*)d_in[20];
  const float* dense_w = (const float*)d_in[21], *dense_b = (const float*)d_in[22];
  const float* ml_w  = (const float*)d_in[23], *ml_b  = (const float*)d_in[24];
  const float* fc1_w = (const float*)d_in[25], *fc1_b = (const float*)d_in[26];
  const float* fc2_w = (const float*)d_in[27], *fc2_b = (const float*)d_in[28];

  float* out = (float*)d_out;

  char* p = (char*)d_ws;
  auto take = [&](size_t bytes) { char* r = p; p += (bytes + 255) & ~(size_t)255; return r; };
  const size_t WD  = (size_t)D_ * D_;
  const size_t WF  = (size_t)DFF_ * D_;
  const size_t ACT = (size_t)M_ * D_;
  const size_t HB  = (size_t)M_ * DFF_;

  unsigned short* wge    = (unsigned short*)take(WD * 2);
  unsigned short* wle1   = (unsigned short*)take(WD * 2);
  unsigned short* wle2   = (unsigned short*)take(WD * 2);
  unsigned short* wqg    = (unsigned short*)take(WD * 2);
  unsigned short* wkg    = (unsigned short*)take(WD * 2);
  unsigned short* wvg    = (unsigned short*)take(WD * 2);
  unsigned short* wqp    = (unsigned short*)take(WD * 2);
  unsigned short* wkp    = (unsigned short*)take(WD * 2);
  unsigned short* wvp    = (unsigned short*)take(WD * 2);
  unsigned short* wdense = (unsigned short*)take(WD * 2);
  unsigned short* wml    = (unsigned short*)take(WD * 2);
  unsigned short* wfc1   = (unsigned short*)take(WF * 2);
  unsigned short* wfc2   = (unsigned short*)take(WF * 2);
  unsigned short* gfb    = (unsigned short*)take(ACT * 2);
  unsigned short* lfb    = (unsigned short*)take(ACT * 2);
  unsigned short* tfb    = (unsigned short*)take(ACT * 2);
  unsigned short* glob   = (unsigned short*)take(ACT * 2);
  unsigned short* loc    = (unsigned short*)take(ACT * 2);
  unsigned short* dup    = (unsigned short*)take(ACT * 2);
  unsigned short* qgb    = (unsigned short*)take(ACT * 2);
  unsigned short* kgb    = (unsigned short*)take(ACT * 2);
  unsigned short* vgb    = (unsigned short*)take(ACT * 2);
  unsigned short* qpb    = (unsigned short*)take(ACT * 2);
  unsigned short* kpb    = (unsigned short*)take(ACT * 2);
  unsigned short* vpb    = (unsigned short*)take(ACT * 2);
  unsigned short* ub     = (unsigned short*)take(ACT * 2);
  unsigned short* lastb  = (unsigned short*)take(ACT * 2);
  unsigned short* out1   = (unsigned short*)take(ACT * 2);
  unsigned short* hbuf   = (unsigned short*)take(HB * 2);
  unsigned short* out2   = (unsigned short*)take(ACT * 2);

  unsigned short* vt1 = gfb;   // dead after stage-1
  unsigned short* vtu = lfb;   // dead after stage-1

  CvtB cb;
  const float* srcs[NCVT] = {ge_w, le1_w, le2_w, qg_w, kg_w, vg_w, qp_w, kp_w, vp_w,
                             dense_w, ml_w, fc1_w, fc2_w, gf, lf, tf};
  unsigned short* dsts[NCVT] = {wge, wle1, wle2, wqg, wkg, wvg, wqp, wkp, wvp,
                                wdense, wml, wfc1, wfc2, gfb, lfb, tfb};
  const int lens[NCVT] = {(int)WD,(int)WD,(int)WD,(int)WD,(int)WD,(int)WD,(int)WD,(int)WD,(int)WD,
                          (int)WD,(int)WD,(int)WF,(int)WF,(int)ACT,(int)ACT,(int)ACT};
  for (int i = 0; i < NCVT; ++i) { cb.s[i] = srcs[i]; cb.d[i] = dsts[i]; cb.n[i] = lens[i]; }
  hipLaunchKernelGGL(cvt_k, dim3(512, NCVT), dim3(256), 0, stream, cb);

  const dim3 blk(256);
  auto mkb = [](std::initializer_list<const unsigned short*> As,
                std::initializer_list<const unsigned short*> Ws,
                std::initializer_list<const float*> Bs,
                std::initializer_list<void*> Ys) {
    GemmB g{};
    int i = 0;
    auto a = As.begin(); auto w = Ws.begin(); auto b = Bs.begin(); auto y = Ys.begin();
    for (; a != As.end(); ++a, ++w, ++b, ++y, ++i) { g.A[i] = *a; g.W[i] = *w; g.bias[i] = *b; g.Y[i] = *y; }
    return g;
  };

  // stage 1: embeddings
  GemmB s1 = mkb({gfb, lfb, lfb}, {wge, wle1, wle2}, {ge_b, le1_b, le2_b},
                 {glob, dup, loc});
  hipLaunchKernelGGL((mgemm<0,0>), dim3(D_/128, M_/128, 3), blk, 0, stream, s1, M_, D_, D_);

  // stage 2: QKV projections
  GemmB s2 = mkb({glob, loc, loc, dup, tfb, tfb}, {wqg, wkg, wvg, wqp, wkp, wvp},
                 {qg_b, kg_b, vg_b, qp_b, kp_b, vp_b}, {qgb, kgb, vgb, qpb, kpb, vpb});
  hipLaunchKernelGGL((mgemm<0,0>), dim3(D_/128, M_/128, 6), blk, 0, stream, s2, M_, D_, D_);

  // attention (bridge collapsed by associativity):
  //   u    = vg + softmax(qp kp^T / 8) @ vp
  //   last = softmax(qg kg^T / 8) @ u
  hipLaunchKernelGGL(vtrans_k, dim3(32, 64), blk, 0, stream, vpb, vt1);
  hipLaunchKernelGGL(attn_mfma_k, dim3(16, 64), blk, 0, stream, qpb, kpb, vt1, vgb, ub);
  hipLaunchKernelGGL(vtrans_k, dim3(32, 64), blk, 0, stream, ub, vtu);
  hipLaunchKernelGGL(attn_mfma_k, dim3(16, 64), blk, 0, stream, qgb, kgb, vtu,
                     (const unsigned short*)nullptr, lastb);

  // tail: dense -> fc1(GELU) -> fc2 -> ml
  GemmB gd = mkb({lastb}, {wdense}, {dense_b}, {out1});
  hipLaunchKernelGGL((mgemm<0,0>), dim3(D_/128, M_/128, 1), blk, 0, stream, gd, M_, D_, D_);
  GemmB g1 = mkb({out1}, {wfc1}, {fc1_b}, {hbuf});
  hipLaunchKernelGGL((mgemm<1,0>), dim3(DFF_/128, M_/128, 1), blk, 0, stream, g1, M_, DFF_, D_);
  GemmB g2 = mkb({hbuf}, {wfc2}, {fc2_b}, {out2});
  hipLaunchKernelGGL((mgemm<0,0>), dim3(D_/128, M_/128, 1), blk, 0, stream, g2, M_, D_, DFF_);
  GemmB gm = mkb({out2}, {wml}, {ml_b}, {out});
  hipLaunchKernelGGL((mgemm<0,1>), dim3(D_/128, M_/128, 1), blk, 0, stream, gm, M_, D_, D_);
}